// Round 1
// baseline (542.829 us; speedup 1.0000x reference)
//
#include <hip/hip_runtime.h>
#include <cstddef>
#include <cstdint>

// ---------------------------------------------------------------------------
// SelfAttention: h = softmax(QK^T*scale - 1e9*mask) @ V, p also output.
// B=8, S=2048, F=D=512. All GEMMs via bf16 MFMA 16x16x32 (m97-style tiles).
// ---------------------------------------------------------------------------

typedef __bf16 bf16_t;
typedef __bf16 bf16x8 __attribute__((ext_vector_type(8)));
typedef float f32x4 __attribute__((ext_vector_type(4)));

#define AS1 __attribute__((address_space(1)))
#define AS3 __attribute__((address_space(3)))

__device__ __forceinline__ void gload_lds16(const void* g, void* l) {
  // async global->LDS, 16B per lane; LDS dst = wave-uniform base + lane*16
  __builtin_amdgcn_global_load_lds((AS1 void*)(g), (AS3 void*)(l), 16, 0, 0);
}

// Stage a 128x32 bf16 tile (row-major, leading dim ld) into LDS [128][32].
__device__ __forceinline__ void stage_bf16_tile(const bf16_t* __restrict__ src, int ld,
                                                bf16_t* lds, int wave, int lane) {
  const int sub = lane >> 2;          // 0..15: row within 16-row group
  const int col = (lane & 3) * 8;     // 4 lanes x 8 bf16 = 32 elems/row
#pragma unroll
  for (int i = 0; i < 2; ++i) {
    const bf16_t* g = src + (size_t)(i * 64 + wave * 16 + sub) * ld + col;
    bf16_t* l = lds + i * 2048 + wave * 512;  // wave-uniform base
    gload_lds16(g, l);
  }
}

// Stage a 128x32 fp32 tile, converting to bf16, into LDS [128][32].
__device__ __forceinline__ void stage_f32_tile(const float* __restrict__ src, int ld,
                                               bf16_t* lds, int tid) {
  const int row = tid >> 1;           // 2 threads per row
  const int col = (tid & 1) * 16;     // 16 floats each
  const float* g = src + (size_t)row * ld + col;
  float4 f[4];
#pragma unroll
  for (int i = 0; i < 4; ++i) f[i] = ((const float4*)g)[i];
  const float* fs = (const float*)f;
  bf16_t tmp[16];
#pragma unroll
  for (int i = 0; i < 16; ++i) tmp[i] = (bf16_t)fs[i];
  bf16x8* dst = (bf16x8*)&lds[row * 32 + col];
  dst[0] = *(const bf16x8*)&tmp[0];
  dst[1] = *(const bf16x8*)&tmp[8];
}

// C[M,N] = A[M,K] * B[N,K]^T.  A: fp32 (converted) or bf16; B: bf16; C: fp32 or bf16.
// grid = (N/128, M/128, Z). If A1 != null, z selects among {A0,A1,A2}; else A = A0 + z*sA.
template <bool A_F32, bool OUT_BF16>
__global__ void gemm_nt(const void* __restrict__ A0, const void* __restrict__ A1,
                        const void* __restrict__ A2, long sA,
                        const bf16_t* __restrict__ Bb, long sB,
                        void* __restrict__ Cb, long sC, int N, int K) {
  __shared__ bf16_t As[128 * 32];
  __shared__ bf16_t Bs[128 * 32];
  const int tid = threadIdx.x;
  const int wave = tid >> 6, lane = tid & 63;
  const int wm = wave >> 1, wn = wave & 1;
  const int z = blockIdx.z;
  const int m_blk = blockIdx.y * 128, n_blk = blockIdx.x * 128;

  const char* Ap;
  if (A1 != nullptr) {
    Ap = (const char*)(z == 0 ? A0 : (z == 1 ? A1 : A2));
  } else {
    Ap = (const char*)A0 + (size_t)z * sA * (A_F32 ? 4 : 2);
  }
  const bf16_t* Btile = Bb + (size_t)z * sB + (size_t)n_blk * K;

  f32x4 acc[4][4] = {};
  const int lq = lane >> 4, lr = lane & 15;

  for (int k0 = 0; k0 < K; k0 += 32) {
    if constexpr (A_F32) {
      stage_bf16_tile(Btile + k0, K, Bs, wave, lane);  // async first
      const float* Atile = (const float*)Ap + (size_t)m_blk * K + k0;
      stage_f32_tile(Atile, K, As, tid);
    } else {
      const bf16_t* Atile = (const bf16_t*)Ap + (size_t)m_blk * K + k0;
      stage_bf16_tile(Atile, K, As, wave, lane);
      stage_bf16_tile(Btile + k0, K, Bs, wave, lane);
    }
    __syncthreads();  // drains vmcnt for global_load_lds + lds writes

    bf16x8 af[4], bfr[4];
#pragma unroll
    for (int i = 0; i < 4; ++i)
      af[i] = *(const bf16x8*)&As[(wm * 64 + i * 16 + lr) * 32 + lq * 8];
#pragma unroll
    for (int i = 0; i < 4; ++i)
      bfr[i] = *(const bf16x8*)&Bs[(wn * 64 + i * 16 + lr) * 32 + lq * 8];
#pragma unroll
    for (int i = 0; i < 4; ++i)
#pragma unroll
      for (int j = 0; j < 4; ++j)
        acc[i][j] = __builtin_amdgcn_mfma_f32_16x16x32_bf16(af[i], bfr[j], acc[i][j], 0, 0, 0);
    __syncthreads();
  }

  // epilogue: C/D layout col=lane&15, row=(lane>>4)*4+reg
  const int row0 = m_blk + wm * 64 + lq * 4;
  const int col0 = n_blk + wn * 64 + lr;
  if constexpr (OUT_BF16) {
    bf16_t* C = (bf16_t*)Cb + (size_t)z * sC;
#pragma unroll
    for (int i = 0; i < 4; ++i)
#pragma unroll
      for (int j = 0; j < 4; ++j)
#pragma unroll
        for (int t = 0; t < 4; ++t)
          C[(size_t)(row0 + i * 16 + t) * N + (col0 + j * 16)] = (bf16_t)acc[i][j][t];
  } else {
    float* C = (float*)Cb + (size_t)z * sC;
#pragma unroll
    for (int i = 0; i < 4; ++i)
#pragma unroll
      for (int j = 0; j < 4; ++j)
#pragma unroll
        for (int t = 0; t < 4; ++t)
          C[(size_t)(row0 + i * 16 + t) * N + (col0 + j * 16)] = acc[i][j][t];
  }
}

// WT[z][d][f] = W_z[f][d], fp32 -> bf16. grid (16,16,3), block (32,8).
__global__ void prep_wt(const float* __restrict__ Wq, const float* __restrict__ Wk,
                        const float* __restrict__ Wv, bf16_t* __restrict__ WT) {
  __shared__ float tile[32][33];
  const int z = blockIdx.z;
  const float* W = z == 0 ? Wq : (z == 1 ? Wk : Wv);
  const int f0 = blockIdx.y * 32, d0 = blockIdx.x * 32;
  const int tx = threadIdx.x, ty = threadIdx.y;
#pragma unroll
  for (int i = 0; i < 32; i += 8) tile[ty + i][tx] = W[(size_t)(f0 + ty + i) * 512 + d0 + tx];
  __syncthreads();
  bf16_t* out = WT + (size_t)z * 512 * 512;
#pragma unroll
  for (int i = 0; i < 32; i += 8)
    out[(size_t)(d0 + ty + i) * 512 + f0 + tx] = (bf16_t)tile[tx][ty + i];
}

// Vt[b][d][s] = V[b][s][d], bf16. grid (16,64,8), block (32,8).
__global__ void transpose_v(const bf16_t* __restrict__ V, bf16_t* __restrict__ Vt) {
  __shared__ bf16_t tile[32][34];
  const int b = blockIdx.z;
  const int s0 = blockIdx.y * 32, d0 = blockIdx.x * 32;
  const int tx = threadIdx.x, ty = threadIdx.y;
  const bf16_t* Vb = V + (size_t)b * 2048 * 512;
  bf16_t* Vtb = Vt + (size_t)b * 512 * 2048;
#pragma unroll
  for (int i = 0; i < 32; i += 8) tile[ty + i][tx] = Vb[(size_t)(s0 + ty + i) * 512 + d0 + tx];
  __syncthreads();
#pragma unroll
  for (int i = 0; i < 32; i += 8)
    Vtb[(size_t)(d0 + ty + i) * 2048 + s0 + tx] = tile[tx][ty + i];
}

// In-place: p = softmax(p*scale - 1e9*mask) per row of 2048. One block (256 thr) per row.
__global__ void softmax_mask(float* __restrict__ p, const float* __restrict__ mask) {
  constexpr int S = 2048;
  constexpr float scale = 0.04419417382415922f;  // 1/sqrt(512)
  const size_t row = blockIdx.x;
  float* pr = p + row * S;
  const float* mr = mask + row * S;
  const int t = threadIdx.x;
  float l[8];
  float mx = -3.4e38f;
#pragma unroll
  for (int i = 0; i < 8; ++i) {
    float raw = pr[t + i * 256];
    float m = mr[t + i * 256];
    float v = raw * scale + m * (-1e9f);
    l[i] = v;
    mx = fmaxf(mx, v);
  }
  __shared__ float red[8];
  for (int off = 32; off > 0; off >>= 1) mx = fmaxf(mx, __shfl_down(mx, off));
  const int wv = t >> 6, ln = t & 63;
  if (ln == 0) red[wv] = mx;
  __syncthreads();
  mx = fmaxf(fmaxf(red[0], red[1]), fmaxf(red[2], red[3]));
  float s = 0.f;
#pragma unroll
  for (int i = 0; i < 8; ++i) {
    float e = __expf(l[i] - mx);
    l[i] = e;
    s += e;
  }
  for (int off = 32; off > 0; off >>= 1) s += __shfl_down(s, off);
  if (ln == 0) red[4 + wv] = s;
  __syncthreads();
  s = red[4] + red[5] + red[6] + red[7];
  const float inv = 1.f / s;
#pragma unroll
  for (int i = 0; i < 8; ++i) pr[t + i * 256] = l[i] * inv;
}

extern "C" void kernel_launch(void* const* d_in, const int* in_sizes, int n_in,
                              void* d_out, int out_size, void* d_ws, size_t ws_size,
                              hipStream_t stream) {
  const int B = 8, S = 2048, F = 512, D = 512;
  const float* q_x = (const float*)d_in[0];
  const float* k_x = (const float*)d_in[1];
  const float* v_x = (const float*)d_in[2];
  const float* mask = (const float*)d_in[3];
  const float* Wq = (const float*)d_in[4];
  const float* Wk = (const float*)d_in[5];
  const float* Wv = (const float*)d_in[6];

  float* h_out = (float*)d_out;                     // [B,S,D]
  float* p_out = h_out + (size_t)B * S * D;         // [B,S,S]

  const size_t BSD = (size_t)B * S * D;             // 8388608
  bf16_t* Q = (bf16_t*)d_ws;                        // [3][B*S*D]: Q,K,V
  bf16_t* Kmat = Q + BSD;
  bf16_t* V = Q + 2 * BSD;
  bf16_t* Vt = Q + 3 * BSD;                         // [B][D][S]
  bf16_t* WT = Vt + BSD;                            // [3][D][F]

  // 1. W -> W^T bf16
  prep_wt<<<dim3(16, 16, 3), dim3(32, 8), 0, stream>>>(Wq, Wk, Wv, WT);

  // 2. projections: {Q,K,V}[16384,512] = x @ W  (NT with W^T)
  gemm_nt<true, true><<<dim3(D / 128, (B * S) / 128, 3), 256, 0, stream>>>(
      q_x, k_x, v_x, 0, WT, (long)D * F, Q, (long)BSD, D, F);

  // 3. V -> V^T
  transpose_v<<<dim3(16, 64, 8), dim3(32, 8), 0, stream>>>(V, Vt);

  // 4. raw scores into d_out p region: p_raw[b] = Q_b @ K_b^T
  gemm_nt<false, false><<<dim3(S / 128, S / 128, 8), 256, 0, stream>>>(
      Q, nullptr, nullptr, (long)S * D, Kmat, (long)S * D, p_out, (long)S * S, S, D);

  // 5. in-place masked softmax
  softmax_mask<<<dim3(B * S), 256, 0, stream>>>(p_out, mask);

  // 6. h[b] = p_b @ V_b  (NT with V^T; p staged fp32->bf16)
  gemm_nt<true, false><<<dim3(D / 128, S / 128, 8), 256, 0, stream>>>(
      p_out, nullptr, nullptr, (long)S * S, Vt, (long)D * S, h_out, (long)S * D, D, S);
}

// Round 2
// 504.154 us; speedup vs baseline: 1.0767x; 1.0767x over previous
//
#include <hip/hip_runtime.h>
#include <cstddef>
#include <cstdint>

// ---------------------------------------------------------------------------
// SelfAttention: h = softmax(QK^T*scale - 1e9*mask) @ V, p also output.
// B=8, S=2048, F=D=512. bf16 MFMA 16x16x32, m97-style 128x128 tiles.
// R2: softmax dual-writes p (fp32 out + bf16 ws); PV reads bf16 p;
//     XCD-aware swizzle (batch->XCD) on QK and PV grids.
// ---------------------------------------------------------------------------

typedef __bf16 bf16_t;
typedef __bf16 bf16x8 __attribute__((ext_vector_type(8)));
typedef float f32x4 __attribute__((ext_vector_type(4)));

#define AS1 __attribute__((address_space(1)))
#define AS3 __attribute__((address_space(3)))

__device__ __forceinline__ void gload_lds16(const void* g, void* l) {
  // async global->LDS, 16B per lane; LDS dst = wave-uniform base + lane*16
  __builtin_amdgcn_global_load_lds((AS1 void*)(g), (AS3 void*)(l), 16, 0, 0);
}

// Stage a 128x32 bf16 tile (row-major, leading dim ld) into LDS [128][32].
__device__ __forceinline__ void stage_bf16_tile(const bf16_t* __restrict__ src, int ld,
                                                bf16_t* lds, int wave, int lane) {
  const int sub = lane >> 2;          // 0..15: row within 16-row group
  const int col = (lane & 3) * 8;     // 4 lanes x 8 bf16 = 32 elems/row
#pragma unroll
  for (int i = 0; i < 2; ++i) {
    const bf16_t* g = src + (size_t)(i * 64 + wave * 16 + sub) * ld + col;
    bf16_t* l = lds + i * 2048 + wave * 512;  // wave-uniform base
    gload_lds16(g, l);
  }
}

// Stage a 128x32 fp32 tile, converting to bf16, into LDS [128][32].
__device__ __forceinline__ void stage_f32_tile(const float* __restrict__ src, int ld,
                                               bf16_t* lds, int tid) {
  const int row = tid >> 1;           // 2 threads per row
  const int col = (tid & 1) * 16;     // 16 floats each
  const float* g = src + (size_t)row * ld + col;
  float4 f[4];
#pragma unroll
  for (int i = 0; i < 4; ++i) f[i] = ((const float4*)g)[i];
  const float* fs = (const float*)f;
  bf16_t tmp[16];
#pragma unroll
  for (int i = 0; i < 16; ++i) tmp[i] = (bf16_t)fs[i];
  bf16x8* dst = (bf16x8*)&lds[row * 32 + col];
  dst[0] = *(const bf16x8*)&tmp[0];
  dst[1] = *(const bf16x8*)&tmp[8];
}

// C[M,N] = A[M,K] * B[N,K]^T.  A: fp32 (converted) or bf16; B: bf16; C: fp32 or bf16.
// NBLK==0: grid = (N/128, M/128, Z); if A1!=null, z selects {A0,A1,A2}.
// NBLK>0:  grid = 1D; z = flat&7 (batch->XCD), m = (flat>>3)/NBLK, n = (flat>>3)%NBLK.
template <bool A_F32, bool OUT_BF16, int NBLK>
__global__ void gemm_nt(const void* __restrict__ A0, const void* __restrict__ A1,
                        const void* __restrict__ A2, long sA,
                        const bf16_t* __restrict__ Bb, long sB,
                        void* __restrict__ Cb, long sC, int N, int K) {
  __shared__ bf16_t As[128 * 32];
  __shared__ bf16_t Bs[128 * 32];
  const int tid = threadIdx.x;
  const int wave = tid >> 6, lane = tid & 63;
  const int wm = wave >> 1, wn = wave & 1;

  int z, m_blk, n_blk;
  if constexpr (NBLK > 0) {
    const int flat = blockIdx.x;
    z = flat & 7;                      // batch -> XCD (round-robin heuristic)
    const int j = flat >> 3;
    n_blk = (j % NBLK) * 128;
    m_blk = (j / NBLK) * 128;
  } else {
    z = blockIdx.z;
    m_blk = blockIdx.y * 128;
    n_blk = blockIdx.x * 128;
  }

  const char* Ap;
  if (A1 != nullptr) {
    Ap = (const char*)(z == 0 ? A0 : (z == 1 ? A1 : A2));
  } else {
    Ap = (const char*)A0 + (size_t)z * sA * (A_F32 ? 4 : 2);
  }
  const bf16_t* Btile = Bb + (size_t)z * sB + (size_t)n_blk * K;

  f32x4 acc[4][4] = {};
  const int lq = lane >> 4, lr = lane & 15;

  for (int k0 = 0; k0 < K; k0 += 32) {
    if constexpr (A_F32) {
      stage_bf16_tile(Btile + k0, K, Bs, wave, lane);  // async first
      const float* Atile = (const float*)Ap + (size_t)m_blk * K + k0;
      stage_f32_tile(Atile, K, As, tid);
    } else {
      const bf16_t* Atile = (const bf16_t*)Ap + (size_t)m_blk * K + k0;
      stage_bf16_tile(Atile, K, As, wave, lane);
      stage_bf16_tile(Btile + k0, K, Bs, wave, lane);
    }
    __syncthreads();  // drains vmcnt for global_load_lds + lds writes

    bf16x8 af[4], bfr[4];
#pragma unroll
    for (int i = 0; i < 4; ++i)
      af[i] = *(const bf16x8*)&As[(wm * 64 + i * 16 + lr) * 32 + lq * 8];
#pragma unroll
    for (int i = 0; i < 4; ++i)
      bfr[i] = *(const bf16x8*)&Bs[(wn * 64 + i * 16 + lr) * 32 + lq * 8];
#pragma unroll
    for (int i = 0; i < 4; ++i)
#pragma unroll
      for (int j = 0; j < 4; ++j)
        acc[i][j] = __builtin_amdgcn_mfma_f32_16x16x32_bf16(af[i], bfr[j], acc[i][j], 0, 0, 0);
    __syncthreads();
  }

  // epilogue: C/D layout col=lane&15, row=(lane>>4)*4+reg
  const int row0 = m_blk + wm * 64 + lq * 4;
  const int col0 = n_blk + wn * 64 + lr;
  if constexpr (OUT_BF16) {
    bf16_t* C = (bf16_t*)Cb + (size_t)z * sC;
#pragma unroll
    for (int i = 0; i < 4; ++i)
#pragma unroll
      for (int j = 0; j < 4; ++j)
#pragma unroll
        for (int t = 0; t < 4; ++t)
          C[(size_t)(row0 + i * 16 + t) * N + (col0 + j * 16)] = (bf16_t)acc[i][j][t];
  } else {
    float* C = (float*)Cb + (size_t)z * sC;
#pragma unroll
    for (int i = 0; i < 4; ++i)
#pragma unroll
      for (int j = 0; j < 4; ++j)
#pragma unroll
        for (int t = 0; t < 4; ++t)
          C[(size_t)(row0 + i * 16 + t) * N + (col0 + j * 16)] = acc[i][j][t];
  }
}

// WT[z][d][f] = W_z[f][d], fp32 -> bf16. grid (16,16,3), block (32,8).
__global__ void prep_wt(const float* __restrict__ Wq, const float* __restrict__ Wk,
                        const float* __restrict__ Wv, bf16_t* __restrict__ WT) {
  __shared__ float tile[32][33];
  const int z = blockIdx.z;
  const float* W = z == 0 ? Wq : (z == 1 ? Wk : Wv);
  const int f0 = blockIdx.y * 32, d0 = blockIdx.x * 32;
  const int tx = threadIdx.x, ty = threadIdx.y;
#pragma unroll
  for (int i = 0; i < 32; i += 8) tile[ty + i][tx] = W[(size_t)(f0 + ty + i) * 512 + d0 + tx];
  __syncthreads();
  bf16_t* out = WT + (size_t)z * 512 * 512;
#pragma unroll
  for (int i = 0; i < 32; i += 8)
    out[(size_t)(d0 + ty + i) * 512 + f0 + tx] = (bf16_t)tile[tx][ty + i];
}

// Vt[b][d][s] = V[b][s][d], bf16. grid (16,64,8), block (32,8).
__global__ void transpose_v(const bf16_t* __restrict__ V, bf16_t* __restrict__ Vt) {
  __shared__ bf16_t tile[32][34];
  const int b = blockIdx.z;
  const int s0 = blockIdx.y * 32, d0 = blockIdx.x * 32;
  const int tx = threadIdx.x, ty = threadIdx.y;
  const bf16_t* Vb = V + (size_t)b * 2048 * 512;
  bf16_t* Vtb = Vt + (size_t)b * 512 * 2048;
#pragma unroll
  for (int i = 0; i < 32; i += 8) tile[ty + i][tx] = Vb[(size_t)(s0 + ty + i) * 512 + d0 + tx];
  __syncthreads();
#pragma unroll
  for (int i = 0; i < 32; i += 8)
    Vtb[(size_t)(d0 + ty + i) * 2048 + s0 + tx] = tile[tx][ty + i];
}

// In-place: p = softmax(p*scale - 1e9*mask) per row of 2048; also store bf16 copy.
__global__ void softmax_mask(float* __restrict__ p, const float* __restrict__ mask,
                             bf16_t* __restrict__ p_bf) {
  constexpr int S = 2048;
  constexpr float scale = 0.04419417382415922f;  // 1/sqrt(512)
  const size_t row = blockIdx.x;
  float* pr = p + row * S;
  bf16_t* pb = p_bf + row * S;
  const float* mr = mask + row * S;
  const int t = threadIdx.x;
  float l[8];
  float mx = -3.4e38f;
#pragma unroll
  for (int i = 0; i < 8; ++i) {
    float raw = pr[t + i * 256];
    float m = mr[t + i * 256];
    float v = raw * scale + m * (-1e9f);
    l[i] = v;
    mx = fmaxf(mx, v);
  }
  __shared__ float red[8];
  for (int off = 32; off > 0; off >>= 1) mx = fmaxf(mx, __shfl_down(mx, off));
  const int wv = t >> 6, ln = t & 63;
  if (ln == 0) red[wv] = mx;
  __syncthreads();
  mx = fmaxf(fmaxf(red[0], red[1]), fmaxf(red[2], red[3]));
  float s = 0.f;
#pragma unroll
  for (int i = 0; i < 8; ++i) {
    float e = __expf(l[i] - mx);
    l[i] = e;
    s += e;
  }
  for (int off = 32; off > 0; off >>= 1) s += __shfl_down(s, off);
  if (ln == 0) red[4 + wv] = s;
  __syncthreads();
  s = red[4] + red[5] + red[6] + red[7];
  const float inv = 1.f / s;
#pragma unroll
  for (int i = 0; i < 8; ++i) {
    float v = l[i] * inv;
    pr[t + i * 256] = v;
    pb[t + i * 256] = (bf16_t)v;
  }
}

extern "C" void kernel_launch(void* const* d_in, const int* in_sizes, int n_in,
                              void* d_out, int out_size, void* d_ws, size_t ws_size,
                              hipStream_t stream) {
  const int B = 8, S = 2048, F = 512, D = 512;
  const float* q_x = (const float*)d_in[0];
  const float* k_x = (const float*)d_in[1];
  const float* v_x = (const float*)d_in[2];
  const float* mask = (const float*)d_in[3];
  const float* Wq = (const float*)d_in[4];
  const float* Wk = (const float*)d_in[5];
  const float* Wv = (const float*)d_in[6];

  float* h_out = (float*)d_out;                     // [B,S,D]
  float* p_out = h_out + (size_t)B * S * D;         // [B,S,S]

  const size_t BSD = (size_t)B * S * D;             // 8388608
  const size_t BSS = (size_t)B * S * S;             // 33554432
  // ws layout (aliased): [0, BSS) bf16 = {Q,K,V while alive} then p_bf;
  // [BSS, BSS+BSD) = Vt; [BSS+BSD, ...) = WT.  Total ~85 MB.
  bf16_t* Q = (bf16_t*)d_ws;                        // [B*S*D]
  bf16_t* Kmat = Q + BSD;
  bf16_t* V = Q + 2 * BSD;
  bf16_t* p_bf = (bf16_t*)d_ws;                     // aliases Q/K/V (dead by softmax)
  bf16_t* Vt = (bf16_t*)d_ws + BSS;                 // [B][D][S]
  bf16_t* WT = Vt + BSD;                            // [3][D][F]

  // 1. W -> W^T bf16
  prep_wt<<<dim3(16, 16, 3), dim3(32, 8), 0, stream>>>(Wq, Wk, Wv, WT);

  // 2. projections: {Q,K,V}[16384,512] = x @ W  (NT with W^T)
  gemm_nt<true, true, 0><<<dim3(D / 128, (B * S) / 128, 3), 256, 0, stream>>>(
      q_x, k_x, v_x, 0, WT, (long)D * F, Q, (long)BSD, D, F);

  // 3. V -> V^T
  transpose_v<<<dim3(16, 64, 8), dim3(32, 8), 0, stream>>>(V, Vt);

  // 4. raw scores into d_out p region: p_raw[b] = Q_b @ K_b^T  (XCD swizzle, NBLK=16)
  gemm_nt<false, false, 16><<<dim3(2048), 256, 0, stream>>>(
      Q, nullptr, nullptr, (long)S * D, Kmat, (long)S * D, p_out, (long)S * S, S, D);

  // 5. in-place masked softmax; dual-write fp32 (output) + bf16 (ws)
  softmax_mask<<<dim3(B * S), 256, 0, stream>>>(p_out, mask, p_bf);

  // 6. h[b] = p_b @ V_b  (pure bf16 NT with V^T; XCD swizzle, NBLK=4)
  gemm_nt<false, false, 4><<<dim3(512), 256, 0, stream>>>(
      p_bf, nullptr, nullptr, (long)S * S, Vt, (long)D * S, h_out, (long)S * D, D, S);
}

// Round 4
// 495.539 us; speedup vs baseline: 1.0954x; 1.0174x over previous
//
#include <hip/hip_runtime.h>
#include <cstddef>
#include <cstdint>

// ---------------------------------------------------------------------------
// SelfAttention: h = softmax(QK^T*scale - 1e9*mask) @ V, p also output.
// B=8, S=2048, F=D=512. bf16 MFMA 16x16x32, m97-style 128x128 tiles.
// R4: R3 with the nontemporal-store type fixed (ext_vector float4, not
//     HIP_vector_type). QK emits bf16 raw scores; softmax reads them +
//     fp32 mask, nontemporal fp32 p out, bf16 p in-place for PV.
// ---------------------------------------------------------------------------

typedef __bf16 bf16_t;
typedef __bf16 bf16x8 __attribute__((ext_vector_type(8)));
typedef float f32x4 __attribute__((ext_vector_type(4)));

#define AS1 __attribute__((address_space(1)))
#define AS3 __attribute__((address_space(3)))

__device__ __forceinline__ void gload_lds16(const void* g, void* l) {
  // async global->LDS, 16B per lane; LDS dst = wave-uniform base + lane*16
  __builtin_amdgcn_global_load_lds((AS1 void*)(g), (AS3 void*)(l), 16, 0, 0);
}

// Stage a 128x32 bf16 tile (row-major, leading dim ld) into LDS [128][32].
__device__ __forceinline__ void stage_bf16_tile(const bf16_t* __restrict__ src, int ld,
                                                bf16_t* lds, int wave, int lane) {
  const int sub = lane >> 2;          // 0..15: row within 16-row group
  const int col = (lane & 3) * 8;     // 4 lanes x 8 bf16 = 32 elems/row
#pragma unroll
  for (int i = 0; i < 2; ++i) {
    const bf16_t* g = src + (size_t)(i * 64 + wave * 16 + sub) * ld + col;
    bf16_t* l = lds + i * 2048 + wave * 512;  // wave-uniform base
    gload_lds16(g, l);
  }
}

// Stage a 128x32 fp32 tile, converting to bf16, into LDS [128][32].
__device__ __forceinline__ void stage_f32_tile(const float* __restrict__ src, int ld,
                                               bf16_t* lds, int tid) {
  const int row = tid >> 1;           // 2 threads per row
  const int col = (tid & 1) * 16;     // 16 floats each
  const float* g = src + (size_t)row * ld + col;
  f32x4 f[4];
#pragma unroll
  for (int i = 0; i < 4; ++i) f[i] = ((const f32x4*)g)[i];
  const float* fs = (const float*)f;
  bf16_t tmp[16];
#pragma unroll
  for (int i = 0; i < 16; ++i) tmp[i] = (bf16_t)fs[i];
  bf16x8* dst = (bf16x8*)&lds[row * 32 + col];
  dst[0] = *(const bf16x8*)&tmp[0];
  dst[1] = *(const bf16x8*)&tmp[8];
}

// C[M,N] = A[M,K] * B[N,K]^T.  A: fp32 (converted) or bf16; B: bf16; C: fp32 or bf16.
// NBLK==0: grid = (N/128, M/128, Z); if A1!=null, z selects {A0,A1,A2}.
// NBLK>0:  grid = 1D; z = flat&7 (batch->XCD), m = (flat>>3)/NBLK, n = (flat>>3)%NBLK.
template <bool A_F32, bool OUT_BF16, int NBLK>
__global__ void gemm_nt(const void* __restrict__ A0, const void* __restrict__ A1,
                        const void* __restrict__ A2, long sA,
                        const bf16_t* __restrict__ Bb, long sB,
                        void* __restrict__ Cb, long sC, int N, int K) {
  __shared__ bf16_t As[128 * 32];
  __shared__ bf16_t Bs[128 * 32];
  const int tid = threadIdx.x;
  const int wave = tid >> 6, lane = tid & 63;
  const int wm = wave >> 1, wn = wave & 1;

  int z, m_blk, n_blk;
  if constexpr (NBLK > 0) {
    const int flat = blockIdx.x;
    z = flat & 7;                      // batch -> XCD (round-robin heuristic)
    const int j = flat >> 3;
    n_blk = (j % NBLK) * 128;
    m_blk = (j / NBLK) * 128;
  } else {
    z = blockIdx.z;
    m_blk = blockIdx.y * 128;
    n_blk = blockIdx.x * 128;
  }

  const char* Ap;
  if (A1 != nullptr) {
    Ap = (const char*)(z == 0 ? A0 : (z == 1 ? A1 : A2));
  } else {
    Ap = (const char*)A0 + (size_t)z * sA * (A_F32 ? 4 : 2);
  }
  const bf16_t* Btile = Bb + (size_t)z * sB + (size_t)n_blk * K;

  f32x4 acc[4][4] = {};
  const int lq = lane >> 4, lr = lane & 15;

  for (int k0 = 0; k0 < K; k0 += 32) {
    if constexpr (A_F32) {
      stage_bf16_tile(Btile + k0, K, Bs, wave, lane);  // async first
      const float* Atile = (const float*)Ap + (size_t)m_blk * K + k0;
      stage_f32_tile(Atile, K, As, tid);
    } else {
      const bf16_t* Atile = (const bf16_t*)Ap + (size_t)m_blk * K + k0;
      stage_bf16_tile(Atile, K, As, wave, lane);
      stage_bf16_tile(Btile + k0, K, Bs, wave, lane);
    }
    __syncthreads();  // drains vmcnt for global_load_lds + lds writes

    bf16x8 af[4], bfr[4];
#pragma unroll
    for (int i = 0; i < 4; ++i)
      af[i] = *(const bf16x8*)&As[(wm * 64 + i * 16 + lr) * 32 + lq * 8];
#pragma unroll
    for (int i = 0; i < 4; ++i)
      bfr[i] = *(const bf16x8*)&Bs[(wn * 64 + i * 16 + lr) * 32 + lq * 8];
#pragma unroll
    for (int i = 0; i < 4; ++i)
#pragma unroll
      for (int j = 0; j < 4; ++j)
        acc[i][j] = __builtin_amdgcn_mfma_f32_16x16x32_bf16(af[i], bfr[j], acc[i][j], 0, 0, 0);
    __syncthreads();
  }

  // epilogue: C/D layout col=lane&15, row=(lane>>4)*4+reg
  const int row0 = m_blk + wm * 64 + lq * 4;
  const int col0 = n_blk + wn * 64 + lr;
  if constexpr (OUT_BF16) {
    bf16_t* C = (bf16_t*)Cb + (size_t)z * sC;
#pragma unroll
    for (int i = 0; i < 4; ++i)
#pragma unroll
      for (int j = 0; j < 4; ++j)
#pragma unroll
        for (int t = 0; t < 4; ++t)
          C[(size_t)(row0 + i * 16 + t) * N + (col0 + j * 16)] = (bf16_t)acc[i][j][t];
  } else {
    float* C = (float*)Cb + (size_t)z * sC;
#pragma unroll
    for (int i = 0; i < 4; ++i)
#pragma unroll
      for (int j = 0; j < 4; ++j)
#pragma unroll
        for (int t = 0; t < 4; ++t)
          C[(size_t)(row0 + i * 16 + t) * N + (col0 + j * 16)] = acc[i][j][t];
  }
}

// WT[z][d][f] = W_z[f][d], fp32 -> bf16. grid (16,16,3), block (32,8).
__global__ void prep_wt(const float* __restrict__ Wq, const float* __restrict__ Wk,
                        const float* __restrict__ Wv, bf16_t* __restrict__ WT) {
  __shared__ float tile[32][33];
  const int z = blockIdx.z;
  const float* W = z == 0 ? Wq : (z == 1 ? Wk : Wv);
  const int f0 = blockIdx.y * 32, d0 = blockIdx.x * 32;
  const int tx = threadIdx.x, ty = threadIdx.y;
#pragma unroll
  for (int i = 0; i < 32; i += 8) tile[ty + i][tx] = W[(size_t)(f0 + ty + i) * 512 + d0 + tx];
  __syncthreads();
  bf16_t* out = WT + (size_t)z * 512 * 512;
#pragma unroll
  for (int i = 0; i < 32; i += 8)
    out[(size_t)(d0 + ty + i) * 512 + f0 + tx] = (bf16_t)tile[tx][ty + i];
}

// Vt[b][d][s] = V[b][s][d], bf16. grid (16,64,8), block (32,8).
__global__ void transpose_v(const bf16_t* __restrict__ V, bf16_t* __restrict__ Vt) {
  __shared__ bf16_t tile[32][34];
  const int b = blockIdx.z;
  const int s0 = blockIdx.y * 32, d0 = blockIdx.x * 32;
  const int tx = threadIdx.x, ty = threadIdx.y;
  const bf16_t* Vb = V + (size_t)b * 2048 * 512;
  bf16_t* Vtb = Vt + (size_t)b * 512 * 2048;
#pragma unroll
  for (int i = 0; i < 32; i += 8) tile[ty + i][tx] = Vb[(size_t)(s0 + ty + i) * 512 + d0 + tx];
  __syncthreads();
#pragma unroll
  for (int i = 0; i < 32; i += 8)
    Vtb[(size_t)(d0 + ty + i) * 2048 + s0 + tx] = tile[tx][ty + i];
}

// p = softmax(s_bf*scale - 1e9*mask) per row of 2048. One 256-thr block per row.
// Reads bf16 raw scores; writes fp32 p (nontemporal, final output) + bf16 p
// in-place over the score buffer (consumed by the PV GEMM).
__global__ void softmax_mask(bf16_t* __restrict__ s_bf, const float* __restrict__ mask,
                             float* __restrict__ p) {
  constexpr int S = 2048;
  constexpr float scale = 0.04419417382415922f;  // 1/sqrt(512)
  const size_t row = blockIdx.x;
  bf16_t* sr = s_bf + row * S;
  float* pr = p + row * S;
  const float* mr = mask + row * S;
  const int t = threadIdx.x;
  const int c0 = t * 8;  // 8 contiguous cols per thread
  bf16x8 sv = *(const bf16x8*)&sr[c0];
  f32x4 m0 = *(const f32x4*)&mr[c0];
  f32x4 m1 = *(const f32x4*)&mr[c0 + 4];
  float l[8];
  float mx = -3.4e38f;
#pragma unroll
  for (int i = 0; i < 8; ++i) {
    float m = (i < 4) ? m0[i & 3] : m1[i & 3];
    float v = (float)sv[i] * scale + m * (-1e9f);
    l[i] = v;
    mx = fmaxf(mx, v);
  }
  __shared__ float red[8];
  for (int off = 32; off > 0; off >>= 1) mx = fmaxf(mx, __shfl_down(mx, off));
  const int wv = t >> 6, ln = t & 63;
  if (ln == 0) red[wv] = mx;
  __syncthreads();
  mx = fmaxf(fmaxf(red[0], red[1]), fmaxf(red[2], red[3]));
  float s = 0.f;
#pragma unroll
  for (int i = 0; i < 8; ++i) {
    float e = __expf(l[i] - mx);
    l[i] = e;
    s += e;
  }
  for (int off = 32; off > 0; off >>= 1) s += __shfl_down(s, off);
  if (ln == 0) red[4 + wv] = s;
  __syncthreads();
  s = red[4] + red[5] + red[6] + red[7];
  const float inv = 1.f / s;
  f32x4 o0, o1;
  bf16x8 ob;
#pragma unroll
  for (int i = 0; i < 8; ++i) {
    float v = l[i] * inv;
    if (i < 4) o0[i & 3] = v; else o1[i & 3] = v;
    ob[i] = (bf16_t)v;
  }
  __builtin_nontemporal_store(o0, (f32x4*)&pr[c0]);
  __builtin_nontemporal_store(o1, (f32x4*)&pr[c0 + 4]);
  *(bf16x8*)&sr[c0] = ob;  // in-place bf16 p for PV
}

extern "C" void kernel_launch(void* const* d_in, const int* in_sizes, int n_in,
                              void* d_out, int out_size, void* d_ws, size_t ws_size,
                              hipStream_t stream) {
  const int B = 8, S = 2048, F = 512, D = 512;
  const float* q_x = (const float*)d_in[0];
  const float* k_x = (const float*)d_in[1];
  const float* v_x = (const float*)d_in[2];
  const float* mask = (const float*)d_in[3];
  const float* Wq = (const float*)d_in[4];
  const float* Wk = (const float*)d_in[5];
  const float* Wv = (const float*)d_in[6];

  float* h_out = (float*)d_out;                     // [B,S,D]
  float* p_out = h_out + (size_t)B * S * D;         // [B,S,S]

  const size_t BSD = (size_t)B * S * D;             // 8388608
  const size_t BSS = (size_t)B * S * S;             // 33554432
  // ws layout: Q,K,V,Vt (4*BSD bf16), WT (3*F*D bf16), s_bf/p_bf (BSS bf16).
  // Total ~136 MB.
  bf16_t* Q = (bf16_t*)d_ws;
  bf16_t* Kmat = Q + BSD;
  bf16_t* V = Q + 2 * BSD;
  bf16_t* Vt = Q + 3 * BSD;                         // [B][D][S]
  bf16_t* WT = Q + 4 * BSD;                         // [3][D][F]
  bf16_t* s_bf = WT + (size_t)3 * F * D;            // [B][S][S] raw scores -> p_bf

  // 1. W -> W^T bf16
  prep_wt<<<dim3(16, 16, 3), dim3(32, 8), 0, stream>>>(Wq, Wk, Wv, WT);

  // 2. projections: {Q,K,V}[16384,512] = x @ W  (NT with W^T)
  gemm_nt<true, true, 0><<<dim3(D / 128, (B * S) / 128, 3), 256, 0, stream>>>(
      q_x, k_x, v_x, 0, WT, (long)D * F, Q, (long)BSD, D, F);

  // 3. V -> V^T
  transpose_v<<<dim3(16, 64, 8), dim3(32, 8), 0, stream>>>(V, Vt);

  // 4. raw scores bf16: s_bf[b] = Q_b @ K_b^T  (XCD swizzle, NBLK=16)
  gemm_nt<false, true, 16><<<dim3(2048), 256, 0, stream>>>(
      Q, nullptr, nullptr, (long)S * D, Kmat, (long)S * D, s_bf, (long)S * S, S, D);

  // 5. masked softmax: fp32 p to d_out (nontemporal) + bf16 p in-place
  softmax_mask<<<dim3(B * S), 256, 0, stream>>>(s_bf, mask, p_out);

  // 6. h[b] = p_b @ V_b  (pure bf16 NT with V^T; XCD swizzle, NBLK=4)
  gemm_nt<false, false, 4><<<dim3(512), 256, 0, stream>>>(
      s_bf, nullptr, nullptr, (long)S * S, Vt, (long)D * S, h_out, (long)S * D, D, S);
}

// Round 5
// 470.511 us; speedup vs baseline: 1.1537x; 1.0532x over previous
//
#include <hip/hip_runtime.h>
#include <cstddef>
#include <cstdint>

// ---------------------------------------------------------------------------
// SelfAttention: h = softmax(QK^T*scale - 1e9*mask) @ V, p also output.
// B=8, S=2048, F=D=512. bf16 MFMA 16x16x32, m97-style 128x128 tiles.
// R5: proj GEMM gets XCD-aware strip swizzle (A-strip reused in-XCD by the
//     4 n-blocks); V-transpose eliminated by computing Vt = Wv^T @ x_v^T
//     directly as an NT GEMM with batch-remapped C stores.
// ---------------------------------------------------------------------------

typedef __bf16 bf16_t;
typedef __bf16 bf16x8 __attribute__((ext_vector_type(8)));
typedef float f32x4 __attribute__((ext_vector_type(4)));

#define AS1 __attribute__((address_space(1)))
#define AS3 __attribute__((address_space(3)))

__device__ __forceinline__ void gload_lds16(const void* g, void* l) {
  // async global->LDS, 16B per lane; LDS dst = wave-uniform base + lane*16
  __builtin_amdgcn_global_load_lds((AS1 void*)(g), (AS3 void*)(l), 16, 0, 0);
}

// Stage a 128x32 bf16 tile (row-major, leading dim ld) into LDS [128][32].
__device__ __forceinline__ void stage_bf16_tile(const bf16_t* __restrict__ src, int ld,
                                                bf16_t* lds, int wave, int lane) {
  const int sub = lane >> 2;          // 0..15: row within 16-row group
  const int col = (lane & 3) * 8;     // 4 lanes x 8 bf16 = 32 elems/row
#pragma unroll
  for (int i = 0; i < 2; ++i) {
    const bf16_t* g = src + (size_t)(i * 64 + wave * 16 + sub) * ld + col;
    bf16_t* l = lds + i * 2048 + wave * 512;  // wave-uniform base
    gload_lds16(g, l);
  }
}

// Stage a 128x32 fp32 tile, converting to bf16, into LDS [128][32].
__device__ __forceinline__ void stage_f32_tile(const float* __restrict__ src, int ld,
                                               bf16_t* lds, int tid) {
  const int row = tid >> 1;           // 2 threads per row
  const int col = (tid & 1) * 16;     // 16 floats each
  const float* g = src + (size_t)row * ld + col;
  f32x4 f[4];
#pragma unroll
  for (int i = 0; i < 4; ++i) f[i] = ((const f32x4*)g)[i];
  const float* fs = (const float*)f;
  bf16_t tmp[16];
#pragma unroll
  for (int i = 0; i < 16; ++i) tmp[i] = (bf16_t)fs[i];
  bf16x8* dst = (bf16x8*)&lds[row * 32 + col];
  dst[0] = *(const bf16x8*)&tmp[0];
  dst[1] = *(const bf16x8*)&tmp[8];
}

// C[M,N] = A[M,K] * B[N,K]^T, 128x128 tile, 4 waves x 4x4 MFMA frags.
// MODE 1 (attention): z = id&7 (batch->XCD), j = id>>3, n = j%NBLK, m = j/NBLK.
// MODE 2 (proj Q/K):  xcd = id&7, j = id>>3 (0..127): n = j&3 (fastest, in-XCD
//                     A-strip reuse), gs = xcd*32 + (j>>2), z = gs>>7 (selects
//                     A0/A1), m = gs&127.
// MODE 3 (Vt):        xcd = id&7, j = id>>3 (0..63): m = j&3 (fastest, in-XCD
//                     B-strip reuse), n_strip = xcd*16 + (j>>2).
// COL_BATCH: C cols are batch-major: store to Cb + (n_blk>>11)*sC with ld 2048.
template <int MODE, int NBLK, bool A_F32, bool B_F32, bool OUT_BF16, bool COL_BATCH>
__global__ void gemm_nt(const void* __restrict__ A0, const void* __restrict__ A1,
                        long sA, const void* __restrict__ B0, long sB,
                        void* __restrict__ Cb, long sC, int N, int K) {
  __shared__ bf16_t As[128 * 32];
  __shared__ bf16_t Bs[128 * 32];
  const int tid = threadIdx.x;
  const int wave = tid >> 6, lane = tid & 63;
  const int wm = wave >> 1, wn = wave & 1;

  const int id = blockIdx.x;
  const int xcd = id & 7, j = id >> 3;
  int z = 0, m_blk, n_blk;
  if constexpr (MODE == 1) {
    z = xcd;
    n_blk = (j % NBLK) * 128;
    m_blk = (j / NBLK) * 128;
  } else if constexpr (MODE == 2) {
    n_blk = (j & 3) * 128;
    const int gs = xcd * 32 + (j >> 2);
    z = gs >> 7;
    m_blk = (gs & 127) * 128;
  } else {  // MODE == 3
    m_blk = (j & 3) * 128;
    n_blk = (xcd * 16 + (j >> 2)) * 128;
  }

  const char* Ap;
  if constexpr (MODE == 2) {
    Ap = (const char*)(z == 0 ? A0 : A1);
  } else {
    Ap = (const char*)A0 + (size_t)z * sA * (A_F32 ? 4 : 2);
  }
  const char* Bp = (const char*)B0 + ((size_t)z * sB + (size_t)n_blk * K) * (B_F32 ? 4 : 2);

  f32x4 acc[4][4] = {};
  const int lq = lane >> 4, lr = lane & 15;

  for (int k0 = 0; k0 < K; k0 += 32) {
    // async bf16 stages first, then VALU fp32 stages
    if constexpr (!A_F32)
      stage_bf16_tile((const bf16_t*)Ap + (size_t)m_blk * K + k0, K, As, wave, lane);
    if constexpr (!B_F32)
      stage_bf16_tile((const bf16_t*)Bp + k0, K, Bs, wave, lane);
    if constexpr (A_F32)
      stage_f32_tile((const float*)Ap + (size_t)m_blk * K + k0, K, As, tid);
    if constexpr (B_F32)
      stage_f32_tile((const float*)Bp + k0, K, Bs, tid);
    __syncthreads();  // drains vmcnt for global_load_lds + lds writes

    bf16x8 af[4], bfr[4];
#pragma unroll
    for (int i = 0; i < 4; ++i)
      af[i] = *(const bf16x8*)&As[(wm * 64 + i * 16 + lr) * 32 + lq * 8];
#pragma unroll
    for (int i = 0; i < 4; ++i)
      bfr[i] = *(const bf16x8*)&Bs[(wn * 64 + i * 16 + lr) * 32 + lq * 8];
#pragma unroll
    for (int i = 0; i < 4; ++i)
#pragma unroll
      for (int jj = 0; jj < 4; ++jj)
        acc[i][jj] = __builtin_amdgcn_mfma_f32_16x16x32_bf16(af[i], bfr[jj], acc[i][jj], 0, 0, 0);
    __syncthreads();
  }

  // epilogue: C/D layout col=lane&15, row=(lane>>4)*4+reg
  const int row0 = m_blk + wm * 64 + lq * 4;
  int col0 = n_blk + wn * 64 + lr;
  size_t cbase = (size_t)z * sC;
  int Nst = N;
  if constexpr (COL_BATCH) {
    cbase = (size_t)(n_blk >> 11) * sC;   // batch from column block
    col0 = (n_blk & 2047) + wn * 64 + lr;
    Nst = 2048;
  }
  if constexpr (OUT_BF16) {
    bf16_t* C = (bf16_t*)Cb + cbase;
#pragma unroll
    for (int i = 0; i < 4; ++i)
#pragma unroll
      for (int jj = 0; jj < 4; ++jj)
#pragma unroll
        for (int t = 0; t < 4; ++t)
          C[(size_t)(row0 + i * 16 + t) * Nst + (col0 + jj * 16)] = (bf16_t)acc[i][jj][t];
  } else {
    float* C = (float*)Cb + cbase;
#pragma unroll
    for (int i = 0; i < 4; ++i)
#pragma unroll
      for (int jj = 0; jj < 4; ++jj)
#pragma unroll
        for (int t = 0; t < 4; ++t)
          C[(size_t)(row0 + i * 16 + t) * Nst + (col0 + jj * 16)] = acc[i][jj][t];
  }
}

// WT[z][d][f] = W_z[f][d], fp32 -> bf16. grid (16,16,3), block (32,8).
__global__ void prep_wt(const float* __restrict__ Wq, const float* __restrict__ Wk,
                        const float* __restrict__ Wv, bf16_t* __restrict__ WT) {
  __shared__ float tile[32][33];
  const int z = blockIdx.z;
  const float* W = z == 0 ? Wq : (z == 1 ? Wk : Wv);
  const int f0 = blockIdx.y * 32, d0 = blockIdx.x * 32;
  const int tx = threadIdx.x, ty = threadIdx.y;
#pragma unroll
  for (int i = 0; i < 32; i += 8) tile[ty + i][tx] = W[(size_t)(f0 + ty + i) * 512 + d0 + tx];
  __syncthreads();
  bf16_t* out = WT + (size_t)z * 512 * 512;
#pragma unroll
  for (int i = 0; i < 32; i += 8)
    out[(size_t)(d0 + ty + i) * 512 + f0 + tx] = (bf16_t)tile[tx][ty + i];
}

// p = softmax(s_bf*scale - 1e9*mask) per row of 2048. One 256-thr block per row.
// Reads bf16 raw scores; writes fp32 p (nontemporal, final output) + bf16 p
// in-place over the score buffer (consumed by the PV GEMM).
__global__ void softmax_mask(bf16_t* __restrict__ s_bf, const float* __restrict__ mask,
                             float* __restrict__ p) {
  constexpr int S = 2048;
  constexpr float scale = 0.04419417382415922f;  // 1/sqrt(512)
  const size_t row = blockIdx.x;
  bf16_t* sr = s_bf + row * S;
  float* pr = p + row * S;
  const float* mr = mask + row * S;
  const int t = threadIdx.x;
  const int c0 = t * 8;  // 8 contiguous cols per thread
  bf16x8 sv = *(const bf16x8*)&sr[c0];
  f32x4 m0 = *(const f32x4*)&mr[c0];
  f32x4 m1 = *(const f32x4*)&mr[c0 + 4];
  float l[8];
  float mx = -3.4e38f;
#pragma unroll
  for (int i = 0; i < 8; ++i) {
    float m = (i < 4) ? m0[i & 3] : m1[i & 3];
    float v = (float)sv[i] * scale + m * (-1e9f);
    l[i] = v;
    mx = fmaxf(mx, v);
  }
  __shared__ float red[8];
  for (int off = 32; off > 0; off >>= 1) mx = fmaxf(mx, __shfl_down(mx, off));
  const int wv = t >> 6, ln = t & 63;
  if (ln == 0) red[wv] = mx;
  __syncthreads();
  mx = fmaxf(fmaxf(red[0], red[1]), fmaxf(red[2], red[3]));
  float s = 0.f;
#pragma unroll
  for (int i = 0; i < 8; ++i) {
    float e = __expf(l[i] - mx);
    l[i] = e;
    s += e;
  }
  for (int off = 32; off > 0; off >>= 1) s += __shfl_down(s, off);
  if (ln == 0) red[4 + wv] = s;
  __syncthreads();
  s = red[4] + red[5] + red[6] + red[7];
  const float inv = 1.f / s;
  f32x4 o0, o1;
  bf16x8 ob;
#pragma unroll
  for (int i = 0; i < 8; ++i) {
    float v = l[i] * inv;
    if (i < 4) o0[i & 3] = v; else o1[i & 3] = v;
    ob[i] = (bf16_t)v;
  }
  __builtin_nontemporal_store(o0, (f32x4*)&pr[c0]);
  __builtin_nontemporal_store(o1, (f32x4*)&pr[c0 + 4]);
  *(bf16x8*)&sr[c0] = ob;  // in-place bf16 p for PV
}

extern "C" void kernel_launch(void* const* d_in, const int* in_sizes, int n_in,
                              void* d_out, int out_size, void* d_ws, size_t ws_size,
                              hipStream_t stream) {
  const int B = 8, S = 2048, F = 512, D = 512;
  const float* q_x = (const float*)d_in[0];
  const float* k_x = (const float*)d_in[1];
  const float* v_x = (const float*)d_in[2];
  const float* mask = (const float*)d_in[3];
  const float* Wq = (const float*)d_in[4];
  const float* Wk = (const float*)d_in[5];
  const float* Wv = (const float*)d_in[6];

  float* h_out = (float*)d_out;                     // [B,S,D]
  float* p_out = h_out + (size_t)B * S * D;         // [B,S,S]

  const size_t BSD = (size_t)B * S * D;             // 8388608
  // ws layout: Q,K (2*BSD), Vt (BSD), WT (3*F*D), s_bf (B*S*S). ~120 MB.
  bf16_t* Q = (bf16_t*)d_ws;
  bf16_t* Kmat = Q + BSD;
  bf16_t* Vt = Q + 2 * BSD;                         // [B][D][S]
  bf16_t* WT = Q + 3 * BSD;                         // [3][D][F]
  bf16_t* s_bf = WT + (size_t)3 * F * D;            // [B][S][S] raw scores -> p_bf

  // 1. W -> W^T bf16 (all three; WT+2*F*D = Wv^T feeds the Vt GEMM)
  prep_wt<<<dim3(16, 16, 3), dim3(32, 8), 0, stream>>>(Wq, Wk, Wv, WT);

  // 2a. Q,K projections: {Q,K}[16384,512] = x @ W  (strip-swizzled, A fp32)
  gemm_nt<2, 0, true, false, true, false><<<dim3(1024), 256, 0, stream>>>(
      q_x, k_x, 0, WT, (long)D * F, Q, (long)BSD, D, F);

  // 2b. Vt[b][d][s] = (Wv^T @ x_v^T): A = Wv^T bf16, B = x_v fp32, batch-remapped C
  gemm_nt<3, 0, false, true, true, true><<<dim3(512), 256, 0, stream>>>(
      WT + (size_t)2 * D * F, nullptr, 0, v_x, 0, Vt, (long)D * S, B * S, F);

  // 3. raw scores bf16: s_bf[b] = Q_b @ K_b^T  (batch->XCD, NBLK=16)
  gemm_nt<1, 16, false, false, true, false><<<dim3(2048), 256, 0, stream>>>(
      Q, nullptr, (long)S * D, Kmat, (long)S * D, s_bf, (long)S * S, S, D);

  // 4. masked softmax: fp32 p to d_out (nontemporal) + bf16 p in-place
  softmax_mask<<<dim3(B * S), 256, 0, stream>>>(s_bf, mask, p_out);

  // 5. h[b] = p_b @ V_b  (pure bf16 NT with Vt; batch->XCD, NBLK=4)
  gemm_nt<1, 4, false, false, false, false><<<dim3(512), 256, 0, stream>>>(
      s_bf, nullptr, (long)S * S, Vt, (long)D * S, h_out, (long)S * D, D, S);
}